// Round 6
// baseline (305.158 us; speedup 1.0000x reference)
//
#include <hip/hip_runtime.h>
#include <math.h>

// ---------------- constants from the reference ----------------
#define NCLS 10
#define TOPK 1000
#define DETS 100
#define CANDMAX 4096
#define SLOTS 16   // 16 * 64 lanes = 1024 >= TOPK
#define ACTK 256   // fast-path active set: 4 slots * 64 lanes

// score histogram: scores > 0.05 have (bits>>16) in [0x3D4C, 0x3F80) -> 564 bins
#define BIN0 0x3D4Cu
#define NBINS 576
#define NBLK 64    // blocks per image for the score/compact passes

__device__ __forceinline__ float sigmoidf_(float x) {
    return 1.0f / (1.0f + expf(-x));
}

__device__ __forceinline__ float key_score(const unsigned long long* key, int c) {
    return __uint_as_float(~(unsigned)(key[c] >> 32));
}

// K1: fused score + per-block LDS histogram (+ optional score cache).
// score = sigmoid(max(logits)) == max(sigmoid(logits)) (sigmoid monotone).
__global__ __launch_bounds__(256) void k_score_hist(const float* __restrict__ logits,
                                                    float* __restrict__ scores,
                                                    unsigned* __restrict__ hist,
                                                    int A, int use_scores) {
    __shared__ unsigned h[NBINS];
    int img = blockIdx.y;
    for (int i = threadIdx.x; i < NBINS; i += 256) h[i] = 0;
    __syncthreads();

    const float* base = logits + (size_t)img * A * NCLS;
    int nquad = A >> 2;   // 4 anchors (= 40 floats = 10 float4) per iteration
    for (int q = blockIdx.x * 256 + threadIdx.x; q < nquad; q += NBLK * 256) {
        const float4* lp = (const float4*)(base + (size_t)q * 40);
        float f[40];
#pragma unroll
        for (int i = 0; i < 10; ++i) ((float4*)f)[i] = lp[i];
        float4 s4;
        float* sv = &s4.x;
#pragma unroll
        for (int j = 0; j < 4; ++j) {
            float m = f[10 * j];
#pragma unroll
            for (int c = 1; c < 10; ++c) m = fmaxf(m, f[10 * j + c]);
            float sc = sigmoidf_(m);
            sc = (sc > 0.05f) ? sc : 0.0f;
            sv[j] = sc;
            if (sc > 0.0f) {
                unsigned bin = (__float_as_uint(sc) >> 16) - BIN0;
                if (bin >= NBINS) bin = NBINS - 1;   // defensive clamp
                atomicAdd(&h[bin], 1u);
            }
        }
        if (use_scores) ((float4*)(scores + (size_t)img * A))[q] = s4;
    }
    // scalar tail (A % 4), handled by block x==0 of each image
    int tail0 = nquad << 2;
    if (blockIdx.x == 0) {
        for (int a = tail0 + (int)threadIdx.x; a < A; a += 256) {
            const float* lp2 = base + (size_t)a * NCLS;
            float m = lp2[0];
            for (int c = 1; c < 10; ++c) m = fmaxf(m, lp2[c]);
            float sc = sigmoidf_(m);
            sc = (sc > 0.05f) ? sc : 0.0f;
            if (use_scores) scores[(size_t)img * A + a] = sc;
            if (sc > 0.0f) {
                unsigned bin = (__float_as_uint(sc) >> 16) - BIN0;
                if (bin >= NBINS) bin = NBINS - 1;
                atomicAdd(&h[bin], 1u);
            }
        }
    }
    __syncthreads();
    for (int i = threadIdx.x; i < NBINS; i += 256) {
        unsigned c = h[i];
        if (c) atomicAdd(&hist[(size_t)img * NBINS + i], c);
    }
}

// K2: per image, single wave: smallest global bin P with suffix count >= TOPK.
__global__ void k_findP(const unsigned* __restrict__ hist, unsigned* __restrict__ P) {
    int img = blockIdx.x;
    int lane = threadIdx.x;               // 64 threads
    const unsigned* h = hist + (size_t)img * NBINS;
    unsigned b[9];
    unsigned s = 0;
#pragma unroll
    for (int j = 0; j < 9; ++j) { b[j] = h[lane * 9 + j]; s += b[j]; }
    unsigned suf = s;                     // inclusive suffix scan across lanes
#pragma unroll
    for (int d = 1; d < 64; d <<= 1) {
        unsigned o = __shfl_down(suf, d);
        if (lane + d < 64) suf += o;
    }
    unsigned above = __shfl_down(suf, 1);
    if (lane == 63) above = 0;
    if (lane == 0 && suf < (unsigned)TOPK) P[img] = 0u;  // pathological fallback
    if (above < (unsigned)TOPK && suf >= (unsigned)TOPK) {
        unsigned cum = above;
        for (int j = 8; j >= 0; --j) {
            cum += b[j];
            if (cum >= (unsigned)TOPK) { P[img] = BIN0 + (unsigned)(lane * 9 + j); break; }
        }
    }
}

// K3: compact candidates (top16 >= P) with wave-aggregated counter atomics.
__global__ __launch_bounds__(256) void k_compact(const float* __restrict__ logits,
                                                 const float* __restrict__ scores,
                                                 const unsigned* __restrict__ P,
                                                 unsigned* __restrict__ ctr,
                                                 unsigned long long* __restrict__ cand,
                                                 int A) {
    int img = blockIdx.y;
    unsigned p = P[img];
    int lane = threadIdx.x & 63;
    int nquad = A >> 2;
    for (int q = blockIdx.x * 256 + threadIdx.x; q < nquad; q += NBLK * 256) {
        float sv[4];
        if (scores) {
            float4 t = ((const float4*)(scores + (size_t)img * A))[q];
            sv[0] = t.x; sv[1] = t.y; sv[2] = t.z; sv[3] = t.w;
        } else {
            const float* lp = logits + ((size_t)img * A + (size_t)q * 4) * NCLS;
            float f[40];
#pragma unroll
            for (int i = 0; i < 10; ++i) ((float4*)f)[i] = ((const float4*)lp)[i];
#pragma unroll
            for (int j = 0; j < 4; ++j) {
                float m = f[10 * j];
#pragma unroll
                for (int c = 1; c < 10; ++c) m = fmaxf(m, f[10 * j + c]);
                float sc = sigmoidf_(m);
                sv[j] = (sc > 0.05f) ? sc : 0.0f;
            }
        }
#pragma unroll
        for (int j = 0; j < 4; ++j) {
            unsigned bits = __float_as_uint(sv[j]);
            bool take = (bits >> 16) >= p;
            unsigned long long mask = __ballot(take);
            if (mask) {
                int cnt = __popcll(mask);
                int leader = __ffsll((unsigned long long)mask) - 1;
                unsigned pos = 0;
                if (lane == leader) pos = atomicAdd(&ctr[img], (unsigned)cnt);
                pos = (unsigned)__shfl((int)pos, leader);
                if (take) {
                    unsigned slot = pos + (unsigned)__popcll(mask & ((1ull << lane) - 1ull));
                    if (slot < CANDMAX) {
                        unsigned a = (unsigned)(q * 4 + j);
                        cand[(size_t)img * CANDMAX + slot] =
                            ((unsigned long long)bits << 32) | (unsigned)(~a);
                    }
                }
            }
        }
    }
    // scalar tail
    int tail0 = nquad << 2;
    if (blockIdx.x == 0) {
        for (int a = tail0 + (int)threadIdx.x; a < A; a += 256) {
            float sc;
            if (scores) sc = scores[(size_t)img * A + a];
            else {
                const float* lp = logits + ((size_t)img * A + a) * NCLS;
                float m = lp[0];
                for (int c = 1; c < 10; ++c) m = fmaxf(m, lp[c]);
                float s = sigmoidf_(m);
                sc = (s > 0.05f) ? s : 0.0f;
            }
            unsigned bits = __float_as_uint(sc);
            if ((bits >> 16) >= p) {
                unsigned pos = atomicAdd(&ctr[img], 1u);
                if (pos < CANDMAX)
                    cand[(size_t)img * CANDMAX + pos] =
                        ((unsigned long long)bits << 32) | (unsigned)(~a);
            }
        }
    }
}

// K4+K5 fused: per-image bitonic sort (adaptive length) -> decode -> soft-NMS
// (frontier fast path over top-256, exact via active-set bound) -> inline
// incremental greedy NMS -> top-100 emit. One block of 1024 threads per image;
// the sort keys stay in LDS, so no top_idx/top_sc global roundtrip.
__global__ __launch_bounds__(1024) void k_sortnms(const unsigned long long* __restrict__ cand,
                                                  const unsigned* __restrict__ ctr,
                                                  const float* __restrict__ logits,
                                                  const float* __restrict__ rel,
                                                  const float* __restrict__ anch,
                                                  float* __restrict__ out, int A, int B) {
    __shared__ unsigned long long key[CANDMAX];
    __shared__ float s_box[TOPK][4];
    __shared__ int   s_lab[TOPK];
    __shared__ float s_pbox[TOPK][4];
    __shared__ int   s_plab[TOPK];
    __shared__ float s_psc[TOPK];
    __shared__ int   s_alive[TOPK];

    const float CLIPV = 4.135166556742356f;  // log(1000/16)
    const float EPS = 1e-7f;
    const float W_ = 1333.0f, H_ = 800.0f;

    int img = blockIdx.x;
    int tid = threadIdx.x;

    // ---- sort phase (all 1024 threads) ----
    unsigned n = ctr[img];
    if (n > CANDMAX) n = CANDMAX;
    int L = (n <= 1024) ? 1024 : (n <= 2048) ? 2048 : CANDMAX;
    for (int i = tid; i < L; i += 1024)
        key[i] = (i < (int)n) ? ~cand[(size_t)img * CANDMAX + i] : ~0ull;
    __syncthreads();
    for (int k = 2; k <= L; k <<= 1) {
        for (int j = k >> 1; j > 0; j >>= 1) {
            for (int i = tid; i < L; i += 1024) {
                int l = i ^ j;
                if (l > i) {
                    unsigned long long va = key[i], vb = key[l];
                    bool up = ((i & k) == 0);
                    if (up ? (va > vb) : (va < vb)) { key[i] = vb; key[l] = va; }
                }
            }
            __syncthreads();
        }
    }
    // pad tail beyond L so key[0..CANDMAX) always valid to read
    for (int i = L + tid; i < CANDMAX; i += 1024) key[i] = ~0ull;
    __syncthreads();

    // ---- Phase A (1024 threads, 1 candidate each): decode into LDS ----
    if (tid < TOPK) {
        unsigned long long ik = key[tid];
        unsigned ai = (unsigned)ik;              // low 32 of ~orig == original index
        if (ai >= (unsigned)A) ai = 0;           // fault insurance (pads/pathological)
        const float* lp = logits + ((size_t)img * A + ai) * NCLS;
        float best = sigmoidf_(lp[0]); int lbb = 0;
#pragma unroll
        for (int cc = 1; cc < NCLS; ++cc) {
            float v = sigmoidf_(lp[cc]);
            if (v > best) { best = v; lbb = cc; }
        }
        const float* rp = rel + ((size_t)img * A + ai) * 4;
        const float* ap = anch + (size_t)ai * 4;
        float a0 = ap[0], a1 = ap[1], a2 = ap[2], a3 = ap[3];
        float wa = a2 - a0, ha = a3 - a1;
        float cxa = a0 + 0.5f * wa, cya = a1 + 0.5f * ha;
        float dx = rp[0], dy = rp[1];
        float dw = fminf(rp[2], CLIPV), dh = fminf(rp[3], CLIPV);
        float cx = dx * wa + cxa, cy = dy * ha + cya;
        float w = expf(dw) * wa, h = expf(dh) * ha;
        s_box[tid][0] = fminf(fmaxf(cx - 0.5f * w, 0.0f), W_);
        s_box[tid][1] = fminf(fmaxf(cy - 0.5f * h, 0.0f), H_);
        s_box[tid][2] = fminf(fmaxf(cx + 0.5f * w, 0.0f), W_);
        s_box[tid][3] = fminf(fmaxf(cy + 0.5f * h, 0.0f), H_);
        s_lab[tid] = lbb;
    }
    __syncthreads();
    if (tid >= 64) return;          // wave 0 only from here; no more barriers
    int lane = tid;

    int M = TOPK;
    int need_full = 0;
    float bound = key_score(key, ACTK);   // init score of first EXCLUDED cand

    // ================= FAST ATTEMPT: 4 slots / 256 candidates =================
    {
        float sc[4], x1[4], y1[4], x2[4], y2[4], ar[4];
        int lb[4];
#pragma unroll
        for (int j = 0; j < 4; ++j) {
            int c = lane + (j << 6);
            float4 bb = *(const float4*)&s_box[c][0];
            x1[j] = bb.x; y1[j] = bb.y; x2[j] = bb.z; y2[j] = bb.w;
            ar[j] = (bb.z - bb.x) * (bb.w - bb.y);
            lb[j] = s_lab[c];
            sc[j] = key_score(key, c);
        }

        // picked-set bitmask: 256 bits in 4 WAVE-UNIFORM u64s (no shuffles)
        unsigned long long pm0 = 0, pm1 = 0, pm2 = 0, pm3 = 0;
        int f = 0, nconf = 0, Mf = -1;

        for (int t = 0; t < ACTK; ++t) {
            float4 fb = *(const float4*)&s_box[f][0];
            int flab = s_lab[f];
            int fs = f >> 6;
            float v = sc[0];
            if (fs == 1) v = sc[1];
            if (fs == 2) v = sc[2];
            if (fs == 3) v = sc[3];
            float cf = __shfl(v, f & 63);
            float lm = fmaxf(fmaxf(sc[0], sc[1]), fmaxf(sc[2], sc[3]));

            int pick; float pcur; float4 pb; int plab_;
            unsigned long long bb2 = __ballot(lm > cf);
            if (bb2 == 0) {
                pick = f; pcur = cf; pb = fb; plab_ = flab;
            } else {
                float bv = sc[0]; int bi = lane;
#pragma unroll
                for (int j = 1; j < 4; ++j) {
                    int e = lane + (j << 6);
                    if (sc[j] > bv) { bv = sc[j]; bi = e; }
                }
#pragma unroll
                for (int d = 32; d; d >>= 1) {
                    float ov = __shfl_xor(bv, d);
                    int oi = __shfl_xor(bi, d);
                    if (ov > bv || (ov == bv && oi < bi)) { bv = ov; bi = oi; }
                }
                pick = bi; pcur = bv;
                pb = *(const float4*)&s_box[pick][0];
                plab_ = s_lab[pick];
            }

            // active-set guard (uniform): excluded cands all have score <= bound
            if (!(pcur >= bound)) { need_full = 1; break; }

            float psc = fmaxf(pcur, 0.0f);
            if (lane == 0) {
                *(float4*)&s_pbox[t][0] = pb;
                s_plab[t] = plab_;
                s_psc[t] = psc;
            }

            // ---- greedy loads issued early (static unroll, clamped addrs) ----
            float4 qb[4]; int ga[4];
#pragma unroll
            for (int k = 0; k < 4; ++k) {
                int p = lane + (k << 6);
                int pc = (p < t) ? p : 0;
                qb[k] = *(const float4*)&s_pbox[pc][0];
                ga[k] = (p < t) ? s_alive[pc] : 0;
            }

            // ---- decay (VALU; overlaps the greedy LDS latency) ----
            float wax = (pb.z - pb.x) * (pb.w - pb.y);
#pragma unroll
            for (int j = 0; j < 4; ++j) {
                float lx2 = fmaxf(pb.x, x1[j]), ly2 = fmaxf(pb.y, y1[j]);
                float rx2 = fminf(pb.z, x2[j]), ry2 = fminf(pb.w, y2[j]);
                float iw2 = fmaxf(rx2 - lx2, 0.0f), ih2 = fmaxf(ry2 - ly2, 0.0f);
                float inter2 = iw2 * ih2;
                bool hot = (inter2 > 0.0f) && (lb[j] == plab_);
                if (__ballot(hot) != 0ull) {
                    float iou2 = inter2 / (wax + ar[j] - inter2 + EPS);
                    float ie = (lb[j] == plab_) ? iou2 : 0.0f;
                    sc[j] *= expf(-(ie * ie) / 0.5f);
                }
                // skipped slots/lanes: factor would be expf(-0.0f) == 1.0f exactly
            }
            // mark picked (after decay, matching the verified ordering)
#pragma unroll
            for (int j = 0; j < 4; ++j)
                if (lane + (j << 6) == pick) sc[j] = -1.0f;

            // ---- greedy compares + ballot (loads have landed under decay) ----
            bool sup = false;
#pragma unroll
            for (int k = 0; k < 4; ++k) {
                if (ga[k]) {
                    float lx = fmaxf(pb.x, qb[k].x), ly = fmaxf(pb.y, qb[k].y);
                    float rx = fminf(pb.z, qb[k].z), ry = fminf(pb.w, qb[k].w);
                    float iw = fmaxf(rx - lx, 0.0f), ih = fmaxf(ry - ly, 0.0f);
                    float inter = iw * ih;
                    float qa = (qb[k].z - qb[k].x) * (qb[k].w - qb[k].y);
                    float iou = inter / (wax + qa - inter + EPS);
                    sup = sup || (iou > 0.8f);
                }
            }
            bool alive = (psc > 0.3f) && (__ballot(sup) == 0ull);
            if (lane == 0) s_alive[t] = alive ? 1 : 0;
            nconf += alive ? 1 : 0;
            if (nconf >= DETS) { Mf = t + 1; break; }

            // ---- picked-mask update + frontier advance (uniform ALU only) ----
            {
                int w2 = pick >> 6;
                unsigned long long b = 1ull << (pick & 63);
                if (w2 == 0) pm0 |= b;
                else if (w2 == 1) pm1 |= b;
                else if (w2 == 2) pm2 |= b;
                else pm3 |= b;
            }
            if (pick == f) {
                // invariant: all indices < f are picked, so first clear bit
                // overall == next frontier
                unsigned long long m0 = ~pm0, m1 = ~pm1, m2 = ~pm2, m3 = ~pm3;
                f = m0 ? (__ffsll(m0) - 1)
                  : m1 ? (64 + __ffsll(m1) - 1)
                  : m2 ? (128 + __ffsll(m2) - 1)
                  : m3 ? (192 + __ffsll(m3) - 1)
                  : ACTK;
                if (f >= ACTK) f = ACTK - 1;   // safe clamp (loop ends by t anyway)
            }
        }
        if (!need_full) {
            if (Mf < 0) need_full = 1;   // exhausted 256 picks with <100 dets
            else M = Mf;
        }
    }

    // ================= FULL FALLBACK: verbatim 16-slot loop =================
    if (need_full) {
        float sc[SLOTS], x1[SLOTS], y1[SLOTS], x2[SLOTS], y2[SLOTS], ar[SLOTS];
        int lb[SLOTS];
#pragma unroll
        for (int j = 0; j < SLOTS; ++j) {
            int c = lane + (j << 6);
            if (c < TOPK) {
                float4 bb = *(const float4*)&s_box[c][0];
                x1[j] = bb.x; y1[j] = bb.y; x2[j] = bb.z; y2[j] = bb.w;
                ar[j] = (bb.z - bb.x) * (bb.w - bb.y);
                lb[j] = s_lab[c];
                sc[j] = key_score(key, c);
            } else {
                sc[j] = -2.0f; lb[j] = -1;
                x1[j] = y1[j] = x2[j] = y2[j] = ar[j] = 0.0f;
            }
        }

        unsigned long long aw = 0;
        if (lane < 15) aw = ~0ull;
        else if (lane == 15) aw = (1ull << (TOPK - 15 * 64)) - 1;   // 40 bits

        int f = 0, nconf = 0;
        M = TOPK;

        for (int t = 0; t < TOPK; ++t) {
            int fp = (f < TOPK) ? f : 0;
            float4 fb = *(const float4*)&s_box[fp][0];
            int flab = s_lab[fp];
            int fs = f >> 6;
            float v = sc[0];
#pragma unroll
            for (int j = 1; j < SLOTS; ++j) if (fs == j) v = sc[j];
            float cf = __shfl(v, f & 63);
            float lm = sc[0];
#pragma unroll
            for (int j = 1; j < SLOTS; ++j) lm = fmaxf(lm, sc[j]);

            int pick; float pcur; float4 pb; int plab_;
            unsigned long long bb2 = __ballot(lm > cf);
            if (bb2 == 0) {
                pick = f; pcur = cf; pb = fb; plab_ = flab;
            } else {
                float bv = sc[0]; int bi = lane;
#pragma unroll
                for (int j = 1; j < SLOTS; ++j) {
                    int e = lane + (j << 6);
                    if (sc[j] > bv) { bv = sc[j]; bi = e; }
                }
#pragma unroll
                for (int d = 32; d; d >>= 1) {
                    float ov = __shfl_xor(bv, d);
                    int oi = __shfl_xor(bi, d);
                    if (ov > bv || (ov == bv && oi < bi)) { bv = ov; bi = oi; }
                }
                pick = bi; pcur = bv;
                pb = *(const float4*)&s_box[pick][0];
                plab_ = s_lab[pick];
            }

            float psc = fmaxf(pcur, 0.0f);
            if (lane == 0) {
                *(float4*)&s_pbox[t][0] = pb;
                s_plab[t] = plab_;
                s_psc[t] = psc;
            }

            bool alive = (psc > 0.3f);
            if (alive && t > 0) {
                float pa = (pb.z - pb.x) * (pb.w - pb.y);
                int kprev = ((t - 1) >> 6) + 1;
                bool sup = false;
                for (int k = 0; k < kprev; ++k) {
                    int p = lane + (k << 6);
                    int pc = (p < t) ? p : 0;
                    float4 qb = *(const float4*)&s_pbox[pc][0];
                    int ga = s_alive[pc];
                    if (p < t && ga) {
                        float lx = fmaxf(pb.x, qb.x), ly = fmaxf(pb.y, qb.y);
                        float rx = fminf(pb.z, qb.z), ry = fminf(pb.w, qb.w);
                        float iw = fmaxf(rx - lx, 0.0f), ih = fmaxf(ry - ly, 0.0f);
                        float inter = iw * ih;
                        float qa = (qb.z - qb.x) * (qb.w - qb.y);
                        float iou = inter / (pa + qa - inter + EPS);
                        sup = sup || (iou > 0.8f);
                    }
                }
                alive = (__ballot(sup) == 0ull);
            }
            if (lane == 0) s_alive[t] = alive ? 1 : 0;
            nconf += alive ? 1 : 0;
            if (nconf >= DETS) { M = t + 1; break; }

            float wax = (pb.z - pb.x) * (pb.w - pb.y);
#pragma unroll
            for (int j = 0; j < SLOTS; ++j) {
                float lx2 = fmaxf(pb.x, x1[j]), ly2 = fmaxf(pb.y, y1[j]);
                float rx2 = fminf(pb.z, x2[j]), ry2 = fminf(pb.w, y2[j]);
                float iw2 = fmaxf(rx2 - lx2, 0.0f), ih2 = fmaxf(ry2 - ly2, 0.0f);
                float inter2 = iw2 * ih2;
                bool hot = (inter2 > 0.0f) && (lb[j] == plab_);
                if (__ballot(hot) != 0ull) {
                    float iou2 = inter2 / (wax + ar[j] - inter2 + EPS);
                    float ie = (lb[j] == plab_) ? iou2 : 0.0f;
                    sc[j] *= expf(-(ie * ie) / 0.5f);
                }
            }
#pragma unroll
            for (int j = 0; j < SLOTS; ++j)
                if (lane + (j << 6) == pick) sc[j] = -1.0f;
            if (lane == (pick >> 6)) aw &= ~(1ull << (pick & 63));

            if (pick == f) {
                int fw = f >> 6;
                unsigned long long w2 = __shfl(aw, fw);
                while (w2 == 0ull && fw < 15) { ++fw; w2 = __shfl(aw, fw); }
                f = (w2 == 0ull) ? TOPK : (fw << 6) + (__ffsll(w2) - 1);
            }
        }
    }

    // ---- emit: alive picks in pick order, then dead padding if needed ----
    float* out_boxes  = out;
    float* out_scores = out + (size_t)B * DETS * 4;
    float* out_labels = out + (size_t)B * DETS * 5;
    int kmax = (M + 63) >> 6;
    int base = 0;
    for (int k = 0; k < kmax; ++k) {
        int p = lane + (k << 6);
        bool av = (p < M) && (s_alive[p] != 0);
        unsigned long long mask = __ballot(av);
        int slot = base + (int)__popcll(mask & ((1ull << lane) - 1ull));
        if (av && slot < DETS) {
            float4 pb = *(const float4*)&s_pbox[p][0];
            float* ob = out_boxes + ((size_t)img * DETS + slot) * 4;
            ob[0] = pb.x; ob[1] = pb.y; ob[2] = pb.z; ob[3] = pb.w;
            out_scores[img * DETS + slot] = s_psc[p];
            out_labels[img * DETS + slot] = (float)s_plab[p];
        }
        base += (int)__popcll(mask);
    }
    if (base < DETS) {
        int dbase = 0;
        for (int k = 0; k < kmax; ++k) {
            int p = lane + (k << 6);
            bool dd = (p < M) && (s_alive[p] == 0);
            unsigned long long mask = __ballot(dd);
            int slot = base + dbase + (int)__popcll(mask & ((1ull << lane) - 1ull));
            if (dd && slot < DETS) {
                float4 pb = *(const float4*)&s_pbox[p][0];
                float* ob = out_boxes + ((size_t)img * DETS + slot) * 4;
                ob[0] = pb.x; ob[1] = pb.y; ob[2] = pb.z; ob[3] = pb.w;
                out_scores[img * DETS + slot] = -1.0f;
                out_labels[img * DETS + slot] = (float)s_plab[p];
            }
            dbase += (int)__popcll(mask);
        }
    }
}

extern "C" void kernel_launch(void* const* d_in, const int* in_sizes, int n_in,
                              void* d_out, int out_size, void* d_ws, size_t ws_size,
                              hipStream_t stream) {
    const float* logits = (const float*)d_in[0];
    const float* rel = (const float*)d_in[1];
    const float* anch = (const float*)d_in[2];
    float* out = (float*)d_out;

    int A = in_sizes[2] / 4;                 // anchors
    int B = in_sizes[0] / (A * NCLS);        // batch

    // workspace layout (all 8B-aligned by construction)
    char* w = (char*)d_ws;
    unsigned* hist = (unsigned*)w;           w += (size_t)B * NBINS * 4;   // 18 KB
    unsigned long long* cand = (unsigned long long*)w; w += (size_t)B * CANDMAX * 8;
    unsigned* P = (unsigned*)w;              w += (size_t)B * 4;
    unsigned* ctr = (unsigned*)w;            w += (size_t)B * 4;
    // optional score cache (6.4 MB at B=8, A=200000) if workspace allows
    float* scores = (float*)w;
    size_t used = (size_t)(w - (char*)d_ws);
    int use_scores = (used + (size_t)B * A * 4 <= ws_size) ? 1 : 0;

    hipMemsetAsync(hist, 0, (size_t)B * NBINS * 4, stream);
    hipMemsetAsync(ctr, 0, (size_t)B * 4, stream);

    dim3 g1(NBLK, (unsigned)B);
    k_score_hist<<<g1, 256, 0, stream>>>(logits, scores, hist, A, use_scores);
    k_findP<<<B, 64, 0, stream>>>(hist, P);
    k_compact<<<g1, 256, 0, stream>>>(logits, use_scores ? scores : nullptr, P, ctr, cand, A);
    k_sortnms<<<B, 1024, 0, stream>>>(cand, ctr, logits, rel, anch, out, A, B);
}

// Round 7
// 290.950 us; speedup vs baseline: 1.0488x; 1.0488x over previous
//
#include <hip/hip_runtime.h>
#include <math.h>

// ---------------- constants from the reference ----------------
#define NCLS 10
#define TOPK 1000
#define DETS 100
#define CANDMAX 4096
#define SLOTS 16   // 16 * 64 lanes = 1024 >= TOPK
#define ACTK 256   // fast-path active set: 4 slots * 64 lanes

// score histogram: scores > 0.05 have (bits>>16) in [0x3D4C, 0x3F80) -> 564 bins
#define BIN0 0x3D4Cu
#define NBINS 576
#define NBLK 64    // blocks per image for the score/compact passes

__device__ __forceinline__ float sigmoidf_(float x) {
    return 1.0f / (1.0f + expf(-x));
}

__device__ __forceinline__ float key_score(const unsigned long long* key, int c) {
    return __uint_as_float(~(unsigned)(key[c] >> 32));
}

// K1: fused score + per-block LDS histogram (+ optional score cache).
// score = sigmoid(max(logits)) == max(sigmoid(logits)) (sigmoid monotone).
__global__ __launch_bounds__(256) void k_score_hist(const float* __restrict__ logits,
                                                    float* __restrict__ scores,
                                                    unsigned* __restrict__ hist,
                                                    int A, int use_scores) {
    __shared__ unsigned h[NBINS];
    int img = blockIdx.y;
    for (int i = threadIdx.x; i < NBINS; i += 256) h[i] = 0;
    __syncthreads();

    const float* base = logits + (size_t)img * A * NCLS;
    int nquad = A >> 2;   // 4 anchors (= 40 floats = 10 float4) per iteration
    for (int q = blockIdx.x * 256 + threadIdx.x; q < nquad; q += NBLK * 256) {
        const float4* lp = (const float4*)(base + (size_t)q * 40);
        float f[40];
#pragma unroll
        for (int i = 0; i < 10; ++i) ((float4*)f)[i] = lp[i];
        float4 s4;
        float* sv = &s4.x;
#pragma unroll
        for (int j = 0; j < 4; ++j) {
            float m = f[10 * j];
#pragma unroll
            for (int c = 1; c < 10; ++c) m = fmaxf(m, f[10 * j + c]);
            float sc = sigmoidf_(m);
            sc = (sc > 0.05f) ? sc : 0.0f;
            sv[j] = sc;
            if (sc > 0.0f) {
                unsigned bin = (__float_as_uint(sc) >> 16) - BIN0;
                if (bin >= NBINS) bin = NBINS - 1;   // defensive clamp
                atomicAdd(&h[bin], 1u);
            }
        }
        if (use_scores) ((float4*)(scores + (size_t)img * A))[q] = s4;
    }
    // scalar tail (A % 4), handled by block x==0 of each image
    int tail0 = nquad << 2;
    if (blockIdx.x == 0) {
        for (int a = tail0 + (int)threadIdx.x; a < A; a += 256) {
            const float* lp2 = base + (size_t)a * NCLS;
            float m = lp2[0];
            for (int c = 1; c < 10; ++c) m = fmaxf(m, lp2[c]);
            float sc = sigmoidf_(m);
            sc = (sc > 0.05f) ? sc : 0.0f;
            if (use_scores) scores[(size_t)img * A + a] = sc;
            if (sc > 0.0f) {
                unsigned bin = (__float_as_uint(sc) >> 16) - BIN0;
                if (bin >= NBINS) bin = NBINS - 1;
                atomicAdd(&h[bin], 1u);
            }
        }
    }
    __syncthreads();
    for (int i = threadIdx.x; i < NBINS; i += 256) {
        unsigned c = h[i];
        if (c) atomicAdd(&hist[(size_t)img * NBINS + i], c);
    }
}

// K2: per image, single wave: smallest global bin P with suffix count >= TOPK.
__global__ void k_findP(const unsigned* __restrict__ hist, unsigned* __restrict__ P) {
    int img = blockIdx.x;
    int lane = threadIdx.x;               // 64 threads
    const unsigned* h = hist + (size_t)img * NBINS;
    unsigned b[9];
    unsigned s = 0;
#pragma unroll
    for (int j = 0; j < 9; ++j) { b[j] = h[lane * 9 + j]; s += b[j]; }
    unsigned suf = s;                     // inclusive suffix scan across lanes
#pragma unroll
    for (int d = 1; d < 64; d <<= 1) {
        unsigned o = __shfl_down(suf, d);
        if (lane + d < 64) suf += o;
    }
    unsigned above = __shfl_down(suf, 1);
    if (lane == 63) above = 0;
    if (lane == 0 && suf < (unsigned)TOPK) P[img] = 0u;  // pathological fallback
    if (above < (unsigned)TOPK && suf >= (unsigned)TOPK) {
        unsigned cum = above;
        for (int j = 8; j >= 0; --j) {
            cum += b[j];
            if (cum >= (unsigned)TOPK) { P[img] = BIN0 + (unsigned)(lane * 9 + j); break; }
        }
    }
}

// K3: compact candidates (top16 >= P) with wave-aggregated counter atomics.
__global__ __launch_bounds__(256) void k_compact(const float* __restrict__ logits,
                                                 const float* __restrict__ scores,
                                                 const unsigned* __restrict__ P,
                                                 unsigned* __restrict__ ctr,
                                                 unsigned long long* __restrict__ cand,
                                                 int A) {
    int img = blockIdx.y;
    unsigned p = P[img];
    int lane = threadIdx.x & 63;
    int nquad = A >> 2;
    for (int q = blockIdx.x * 256 + threadIdx.x; q < nquad; q += NBLK * 256) {
        float sv[4];
        if (scores) {
            float4 t = ((const float4*)(scores + (size_t)img * A))[q];
            sv[0] = t.x; sv[1] = t.y; sv[2] = t.z; sv[3] = t.w;
        } else {
            const float* lp = logits + ((size_t)img * A + (size_t)q * 4) * NCLS;
            float f[40];
#pragma unroll
            for (int i = 0; i < 10; ++i) ((float4*)f)[i] = ((const float4*)lp)[i];
#pragma unroll
            for (int j = 0; j < 4; ++j) {
                float m = f[10 * j];
#pragma unroll
                for (int c = 1; c < 10; ++c) m = fmaxf(m, f[10 * j + c]);
                float sc = sigmoidf_(m);
                sv[j] = (sc > 0.05f) ? sc : 0.0f;
            }
        }
#pragma unroll
        for (int j = 0; j < 4; ++j) {
            unsigned bits = __float_as_uint(sv[j]);
            bool take = (bits >> 16) >= p;
            unsigned long long mask = __ballot(take);
            if (mask) {
                int cnt = __popcll(mask);
                int leader = __ffsll((unsigned long long)mask) - 1;
                unsigned pos = 0;
                if (lane == leader) pos = atomicAdd(&ctr[img], (unsigned)cnt);
                pos = (unsigned)__shfl((int)pos, leader);
                if (take) {
                    unsigned slot = pos + (unsigned)__popcll(mask & ((1ull << lane) - 1ull));
                    if (slot < CANDMAX) {
                        unsigned a = (unsigned)(q * 4 + j);
                        cand[(size_t)img * CANDMAX + slot] =
                            ((unsigned long long)bits << 32) | (unsigned)(~a);
                    }
                }
            }
        }
    }
    // scalar tail
    int tail0 = nquad << 2;
    if (blockIdx.x == 0) {
        for (int a = tail0 + (int)threadIdx.x; a < A; a += 256) {
            float sc;
            if (scores) sc = scores[(size_t)img * A + a];
            else {
                const float* lp = logits + ((size_t)img * A + a) * NCLS;
                float m = lp[0];
                for (int c = 1; c < 10; ++c) m = fmaxf(m, lp[c]);
                float s = sigmoidf_(m);
                sc = (s > 0.05f) ? s : 0.0f;
            }
            unsigned bits = __float_as_uint(sc);
            if ((bits >> 16) >= p) {
                unsigned pos = atomicAdd(&ctr[img], 1u);
                if (pos < CANDMAX)
                    cand[(size_t)img * CANDMAX + pos] =
                        ((unsigned long long)bits << 32) | (unsigned)(~a);
            }
        }
    }
}

// K4+K5 fused: per-image bitonic sort (adaptive length) -> decode -> soft-NMS
// with CLEAN-FRONTIER fast path -> inline incremental greedy NMS -> top-100.
//
// Clean frontier: a uniform 256-bit skip mask tracks picked OR decayed
// candidates (decay bits fall out of the per-slot hot ballots for free).
// The frontier f = lowest index with skip bit clear; since f was never
// decayed, its CURRENT score == INITIAL score == key_score(key,f): a
// uniform LDS read, no cross-lane shuffle on the serial chain. Pick test:
// per-lane best (bv,bi) + ONE ballot of (bv>cf || (bv==cf && bi<f)) --
// exact argmax tie semantics (lowest index wins). Fast-path guard vs
// excluded candidates is auto-satisfied: cf = s_f >= s_256 = bound (sorted),
// ties resolve to the lower index f. Slow path (rare, self-limiting:
// micro-decayed candidates still near the top) keeps the full reduce + guard.
__global__ __launch_bounds__(1024) void k_sortnms(const unsigned long long* __restrict__ cand,
                                                  const unsigned* __restrict__ ctr,
                                                  const float* __restrict__ logits,
                                                  const float* __restrict__ rel,
                                                  const float* __restrict__ anch,
                                                  float* __restrict__ out, int A, int B) {
    __shared__ unsigned long long key[CANDMAX];
    __shared__ float s_box[TOPK][4];
    __shared__ int   s_lab[TOPK];
    __shared__ float s_pbox[TOPK][4];
    __shared__ int   s_plab[TOPK];
    __shared__ float s_psc[TOPK];
    __shared__ int   s_alive[TOPK];

    const float CLIPV = 4.135166556742356f;  // log(1000/16)
    const float EPS = 1e-7f;
    const float W_ = 1333.0f, H_ = 800.0f;

    int img = blockIdx.x;
    int tid = threadIdx.x;

    // ---- sort phase (all 1024 threads) ----
    unsigned n = ctr[img];
    if (n > CANDMAX) n = CANDMAX;
    int L = (n <= 1024) ? 1024 : (n <= 2048) ? 2048 : CANDMAX;
    for (int i = tid; i < L; i += 1024)
        key[i] = (i < (int)n) ? ~cand[(size_t)img * CANDMAX + i] : ~0ull;
    __syncthreads();
    for (int k = 2; k <= L; k <<= 1) {
        for (int j = k >> 1; j > 0; j >>= 1) {
            for (int i = tid; i < L; i += 1024) {
                int l = i ^ j;
                if (l > i) {
                    unsigned long long va = key[i], vb = key[l];
                    bool up = ((i & k) == 0);
                    if (up ? (va > vb) : (va < vb)) { key[i] = vb; key[l] = va; }
                }
            }
            __syncthreads();
        }
    }
    // pad tail beyond L so key[0..CANDMAX) always valid to read
    for (int i = L + tid; i < CANDMAX; i += 1024) key[i] = ~0ull;
    __syncthreads();

    // ---- Phase A (1024 threads, 1 candidate each): decode into LDS ----
    if (tid < TOPK) {
        unsigned long long ik = key[tid];
        unsigned ai = (unsigned)ik;              // low 32 of ~orig == original index
        if (ai >= (unsigned)A) ai = 0;           // fault insurance (pads/pathological)
        const float* lp = logits + ((size_t)img * A + ai) * NCLS;
        float best = sigmoidf_(lp[0]); int lbb = 0;
#pragma unroll
        for (int cc = 1; cc < NCLS; ++cc) {
            float v = sigmoidf_(lp[cc]);
            if (v > best) { best = v; lbb = cc; }
        }
        const float* rp = rel + ((size_t)img * A + ai) * 4;
        const float* ap = anch + (size_t)ai * 4;
        float a0 = ap[0], a1 = ap[1], a2 = ap[2], a3 = ap[3];
        float wa = a2 - a0, ha = a3 - a1;
        float cxa = a0 + 0.5f * wa, cya = a1 + 0.5f * ha;
        float dx = rp[0], dy = rp[1];
        float dw = fminf(rp[2], CLIPV), dh = fminf(rp[3], CLIPV);
        float cx = dx * wa + cxa, cy = dy * ha + cya;
        float w = expf(dw) * wa, h = expf(dh) * ha;
        s_box[tid][0] = fminf(fmaxf(cx - 0.5f * w, 0.0f), W_);
        s_box[tid][1] = fminf(fmaxf(cy - 0.5f * h, 0.0f), H_);
        s_box[tid][2] = fminf(fmaxf(cx + 0.5f * w, 0.0f), W_);
        s_box[tid][3] = fminf(fmaxf(cy + 0.5f * h, 0.0f), H_);
        s_lab[tid] = lbb;
    }
    __syncthreads();
    if (tid >= 64) return;          // wave 0 only from here; no more barriers
    int lane = tid;

    int M = TOPK;
    int need_full = 0;
    float bound = key_score(key, ACTK);   // init score of first EXCLUDED cand

    // ================= FAST ATTEMPT: clean-frontier, 4 slots =================
    {
        float sc[4], x1[4], y1[4], x2[4], y2[4], ar[4];
        int lb[4];
#pragma unroll
        for (int j = 0; j < 4; ++j) {
            int c = lane + (j << 6);
            float4 bb = *(const float4*)&s_box[c][0];
            x1[j] = bb.x; y1[j] = bb.y; x2[j] = bb.z; y2[j] = bb.w;
            ar[j] = (bb.z - bb.x) * (bb.w - bb.y);
            lb[j] = s_lab[c];
            sc[j] = key_score(key, c);
        }

        // uniform skip masks: picked OR decayed; word s covers [64s, 64s+64)
        unsigned long long skip0 = 0, skip1 = 0, skip2 = 0, skip3 = 0;
        int f = 0, nconf = 0, Mf = -1;
        float cf = key_score(key, 0);
        float4 fb = *(const float4*)&s_box[0][0];
        int flab = s_lab[0];

        for (int t = 0; t < ACTK; ++t) {
            // per-lane best (value desc, index asc; slot order = ascending idx)
            float bv = sc[0]; int bi = lane;
#pragma unroll
            for (int j = 1; j < 4; ++j) {
                int e = lane + (j << 6);
                if (sc[j] > bv) { bv = sc[j]; bi = e; }
            }
            bool beat = (f < ACTK) ? (bv > cf || (bv == cf && bi < f))
                                   : (bv > -0.5f);
            unsigned long long bb2 = __ballot(beat);

            int pick; float pcur; float4 pb; int plab_;
            if (bb2 == 0) {
                // common path: clean frontier is the exact argmax
                pick = f; pcur = cf; pb = fb; plab_ = flab;
            } else {
                // rare path: full argmax reduce (value desc, index asc)
                float rv = bv; int ri = bi;
#pragma unroll
                for (int d = 32; d; d >>= 1) {
                    float ov = __shfl_xor(rv, d);
                    int oi = __shfl_xor(ri, d);
                    if (ov > rv || (ov == rv && oi < ri)) { rv = ov; ri = oi; }
                }
                pick = ri; pcur = rv;
                pb = *(const float4*)&s_box[pick][0];
                plab_ = s_lab[pick];
                // active-set guard: excluded cands all have score <= bound
                if (!(pcur >= bound)) { need_full = 1; break; }
            }

            float psc = fmaxf(pcur, 0.0f);
            if (lane == 0) {
                *(float4*)&s_pbox[t][0] = pb;
                s_plab[t] = plab_;
                s_psc[t] = psc;
            }

            // ---- greedy loads issued early (static unroll, clamped addrs) ----
            float4 qb[4]; int ga[4];
#pragma unroll
            for (int k = 0; k < 4; ++k) {
                int p = lane + (k << 6);
                int pc = (p < t) ? p : 0;
                qb[k] = *(const float4*)&s_pbox[pc][0];
                ga[k] = (p < t) ? s_alive[pc] : 0;
            }

            // ---- decay (ballot-skip); hot masks feed the skip words for free ----
            float wax = (pb.z - pb.x) * (pb.w - pb.y);
#pragma unroll
            for (int j = 0; j < 4; ++j) {
                float lx2 = fmaxf(pb.x, x1[j]), ly2 = fmaxf(pb.y, y1[j]);
                float rx2 = fminf(pb.z, x2[j]), ry2 = fminf(pb.w, y2[j]);
                float iw2 = fmaxf(rx2 - lx2, 0.0f), ih2 = fmaxf(ry2 - ly2, 0.0f);
                float inter2 = iw2 * ih2;
                bool hot = (inter2 > 0.0f) && (lb[j] == plab_);
                unsigned long long hm = __ballot(hot);
                if (hm != 0ull) {
                    float iou2 = inter2 / (wax + ar[j] - inter2 + EPS);
                    float ie = (lb[j] == plab_) ? iou2 : 0.0f;
                    sc[j] *= expf(-(ie * ie) / 0.5f);
                    // non-hot lanes multiply by expf(-0.0f)==1.0f: bit-identical
                }
                if (j == 0) skip0 |= hm;
                else if (j == 1) skip1 |= hm;
                else if (j == 2) skip2 |= hm;
                else skip3 |= hm;
            }
            // mark picked (after decay, matching the verified ordering)
#pragma unroll
            for (int j = 0; j < 4; ++j)
                if (lane + (j << 6) == pick) sc[j] = -1.0f;
            {
                int w2 = pick >> 6;
                unsigned long long b = 1ull << (pick & 63);
                if (w2 == 0) skip0 |= b;
                else if (w2 == 1) skip1 |= b;
                else if (w2 == 2) skip2 |= b;
                else skip3 |= b;
            }

            // ---- greedy compares + ballot (loads landed under decay) ----
            bool sup = false;
#pragma unroll
            for (int k = 0; k < 4; ++k) {
                if (ga[k]) {
                    float lx = fmaxf(pb.x, qb[k].x), ly = fmaxf(pb.y, qb[k].y);
                    float rx = fminf(pb.z, qb[k].z), ry = fminf(pb.w, qb[k].w);
                    float iw = fmaxf(rx - lx, 0.0f), ih = fmaxf(ry - ly, 0.0f);
                    float inter = iw * ih;
                    float qa = (qb[k].z - qb[k].x) * (qb[k].w - qb[k].y);
                    float iou = inter / (wax + qa - inter + EPS);
                    sup = sup || (iou > 0.8f);
                }
            }
            bool alive = (psc > 0.3f) && (__ballot(sup) == 0ull);
            if (lane == 0) s_alive[t] = alive ? 1 : 0;
            nconf += alive ? 1 : 0;
            if (nconf >= DETS) { Mf = t + 1; break; }

            // ---- frontier advance: next clear skip bit >= f (uniform ALU) ----
            {
                int fw = f >> 6;
                unsigned long long m =
                    ((fw == 0) ? ~skip0 : (fw == 1) ? ~skip1 : (fw == 2) ? ~skip2 : ~skip3)
                    & (~0ull << (f & 63));
                while (m == 0ull && fw < 3) {
                    ++fw;
                    m = (fw == 1) ? ~skip1 : (fw == 2) ? ~skip2 : ~skip3;
                }
                f = (m == 0ull) ? ACTK : (fw << 6) + (__ffsll(m) - 1);
            }
            if (f < ACTK) {
                cf = key_score(key, f);
                fb = *(const float4*)&s_box[f][0];
                flab = s_lab[f];
            } else {
                cf = -0.5f;   // forces slow path; all remaining actives decayed
            }
        }
        if (!need_full) {
            if (Mf < 0) need_full = 1;   // exhausted 256 picks with <100 dets
            else M = Mf;
        }
    }

    // ================= FULL FALLBACK: verbatim 16-slot loop =================
    if (need_full) {
        float sc[SLOTS], x1[SLOTS], y1[SLOTS], x2[SLOTS], y2[SLOTS], ar[SLOTS];
        int lb[SLOTS];
#pragma unroll
        for (int j = 0; j < SLOTS; ++j) {
            int c = lane + (j << 6);
            if (c < TOPK) {
                float4 bb = *(const float4*)&s_box[c][0];
                x1[j] = bb.x; y1[j] = bb.y; x2[j] = bb.z; y2[j] = bb.w;
                ar[j] = (bb.z - bb.x) * (bb.w - bb.y);
                lb[j] = s_lab[c];
                sc[j] = key_score(key, c);
            } else {
                sc[j] = -2.0f; lb[j] = -1;
                x1[j] = y1[j] = x2[j] = y2[j] = ar[j] = 0.0f;
            }
        }

        unsigned long long aw = 0;
        if (lane < 15) aw = ~0ull;
        else if (lane == 15) aw = (1ull << (TOPK - 15 * 64)) - 1;   // 40 bits

        int f = 0, nconf = 0;
        M = TOPK;

        for (int t = 0; t < TOPK; ++t) {
            int fp = (f < TOPK) ? f : 0;
            float4 fb = *(const float4*)&s_box[fp][0];
            int flab = s_lab[fp];
            int fs = f >> 6;
            float v = sc[0];
#pragma unroll
            for (int j = 1; j < SLOTS; ++j) if (fs == j) v = sc[j];
            float cf = __shfl(v, f & 63);
            float lm = sc[0];
#pragma unroll
            for (int j = 1; j < SLOTS; ++j) lm = fmaxf(lm, sc[j]);

            int pick; float pcur; float4 pb; int plab_;
            unsigned long long bb2 = __ballot(lm > cf);
            if (bb2 == 0) {
                pick = f; pcur = cf; pb = fb; plab_ = flab;
            } else {
                float bv = sc[0]; int bi = lane;
#pragma unroll
                for (int j = 1; j < SLOTS; ++j) {
                    int e = lane + (j << 6);
                    if (sc[j] > bv) { bv = sc[j]; bi = e; }
                }
#pragma unroll
                for (int d = 32; d; d >>= 1) {
                    float ov = __shfl_xor(bv, d);
                    int oi = __shfl_xor(bi, d);
                    if (ov > bv || (ov == bv && oi < bi)) { bv = ov; bi = oi; }
                }
                pick = bi; pcur = bv;
                pb = *(const float4*)&s_box[pick][0];
                plab_ = s_lab[pick];
            }

            float psc = fmaxf(pcur, 0.0f);
            if (lane == 0) {
                *(float4*)&s_pbox[t][0] = pb;
                s_plab[t] = plab_;
                s_psc[t] = psc;
            }

            bool alive = (psc > 0.3f);
            if (alive && t > 0) {
                float pa = (pb.z - pb.x) * (pb.w - pb.y);
                int kprev = ((t - 1) >> 6) + 1;
                bool sup = false;
                for (int k = 0; k < kprev; ++k) {
                    int p = lane + (k << 6);
                    int pc = (p < t) ? p : 0;
                    float4 qb = *(const float4*)&s_pbox[pc][0];
                    int ga = s_alive[pc];
                    if (p < t && ga) {
                        float lx = fmaxf(pb.x, qb.x), ly = fmaxf(pb.y, qb.y);
                        float rx = fminf(pb.z, qb.z), ry = fminf(pb.w, qb.w);
                        float iw = fmaxf(rx - lx, 0.0f), ih = fmaxf(ry - ly, 0.0f);
                        float inter = iw * ih;
                        float qa = (qb.z - qb.x) * (qb.w - qb.y);
                        float iou = inter / (pa + qa - inter + EPS);
                        sup = sup || (iou > 0.8f);
                    }
                }
                alive = (__ballot(sup) == 0ull);
            }
            if (lane == 0) s_alive[t] = alive ? 1 : 0;
            nconf += alive ? 1 : 0;
            if (nconf >= DETS) { M = t + 1; break; }

            float wax = (pb.z - pb.x) * (pb.w - pb.y);
#pragma unroll
            for (int j = 0; j < SLOTS; ++j) {
                float lx2 = fmaxf(pb.x, x1[j]), ly2 = fmaxf(pb.y, y1[j]);
                float rx2 = fminf(pb.z, x2[j]), ry2 = fminf(pb.w, y2[j]);
                float iw2 = fmaxf(rx2 - lx2, 0.0f), ih2 = fmaxf(ry2 - ly2, 0.0f);
                float inter2 = iw2 * ih2;
                bool hot = (inter2 > 0.0f) && (lb[j] == plab_);
                if (__ballot(hot) != 0ull) {
                    float iou2 = inter2 / (wax + ar[j] - inter2 + EPS);
                    float ie = (lb[j] == plab_) ? iou2 : 0.0f;
                    sc[j] *= expf(-(ie * ie) / 0.5f);
                }
            }
#pragma unroll
            for (int j = 0; j < SLOTS; ++j)
                if (lane + (j << 6) == pick) sc[j] = -1.0f;
            if (lane == (pick >> 6)) aw &= ~(1ull << (pick & 63));

            if (pick == f) {
                int fw = f >> 6;
                unsigned long long w2 = __shfl(aw, fw);
                while (w2 == 0ull && fw < 15) { ++fw; w2 = __shfl(aw, fw); }
                f = (w2 == 0ull) ? TOPK : (fw << 6) + (__ffsll(w2) - 1);
            }
        }
    }

    // ---- emit: alive picks in pick order, then dead padding if needed ----
    float* out_boxes  = out;
    float* out_scores = out + (size_t)B * DETS * 4;
    float* out_labels = out + (size_t)B * DETS * 5;
    int kmax = (M + 63) >> 6;
    int base = 0;
    for (int k = 0; k < kmax; ++k) {
        int p = lane + (k << 6);
        bool av = (p < M) && (s_alive[p] != 0);
        unsigned long long mask = __ballot(av);
        int slot = base + (int)__popcll(mask & ((1ull << lane) - 1ull));
        if (av && slot < DETS) {
            float4 pb = *(const float4*)&s_pbox[p][0];
            float* ob = out_boxes + ((size_t)img * DETS + slot) * 4;
            ob[0] = pb.x; ob[1] = pb.y; ob[2] = pb.z; ob[3] = pb.w;
            out_scores[img * DETS + slot] = s_psc[p];
            out_labels[img * DETS + slot] = (float)s_plab[p];
        }
        base += (int)__popcll(mask);
    }
    if (base < DETS) {
        int dbase = 0;
        for (int k = 0; k < kmax; ++k) {
            int p = lane + (k << 6);
            bool dd = (p < M) && (s_alive[p] == 0);
            unsigned long long mask = __ballot(dd);
            int slot = base + dbase + (int)__popcll(mask & ((1ull << lane) - 1ull));
            if (dd && slot < DETS) {
                float4 pb = *(const float4*)&s_pbox[p][0];
                float* ob = out_boxes + ((size_t)img * DETS + slot) * 4;
                ob[0] = pb.x; ob[1] = pb.y; ob[2] = pb.z; ob[3] = pb.w;
                out_scores[img * DETS + slot] = -1.0f;
                out_labels[img * DETS + slot] = (float)s_plab[p];
            }
            dbase += (int)__popcll(mask);
        }
    }
}

extern "C" void kernel_launch(void* const* d_in, const int* in_sizes, int n_in,
                              void* d_out, int out_size, void* d_ws, size_t ws_size,
                              hipStream_t stream) {
    const float* logits = (const float*)d_in[0];
    const float* rel = (const float*)d_in[1];
    const float* anch = (const float*)d_in[2];
    float* out = (float*)d_out;

    int A = in_sizes[2] / 4;                 // anchors
    int B = in_sizes[0] / (A * NCLS);        // batch

    // workspace layout (all 8B-aligned by construction)
    char* w = (char*)d_ws;
    unsigned* hist = (unsigned*)w;           w += (size_t)B * NBINS * 4;   // 18 KB
    unsigned long long* cand = (unsigned long long*)w; w += (size_t)B * CANDMAX * 8;
    unsigned* P = (unsigned*)w;              w += (size_t)B * 4;
    unsigned* ctr = (unsigned*)w;            w += (size_t)B * 4;
    // optional score cache (6.4 MB at B=8, A=200000) if workspace allows
    float* scores = (float*)w;
    size_t used = (size_t)(w - (char*)d_ws);
    int use_scores = (used + (size_t)B * A * 4 <= ws_size) ? 1 : 0;

    hipMemsetAsync(hist, 0, (size_t)B * NBINS * 4, stream);
    hipMemsetAsync(ctr, 0, (size_t)B * 4, stream);

    dim3 g1(NBLK, (unsigned)B);
    k_score_hist<<<g1, 256, 0, stream>>>(logits, scores, hist, A, use_scores);
    k_findP<<<B, 64, 0, stream>>>(hist, P);
    k_compact<<<g1, 256, 0, stream>>>(logits, use_scores ? scores : nullptr, P, ctr, cand, A);
    k_sortnms<<<B, 1024, 0, stream>>>(cand, ctr, logits, rel, anch, out, A, B);
}